// Round 8
// baseline (1165.532 us; speedup 1.0000x reference)
//
#include <hip/hip_runtime.h>

typedef short bf16x8 __attribute__((ext_vector_type(8)));
typedef float f32x4  __attribute__((ext_vector_type(4)));
typedef unsigned short u16;

#define B_ 4
#define R_ 36
#define RP 48          // r padded to 3 m-tiles of 16
#define C_ 3
#define H_ 384
#define W_ 224
#define KS 64
#define OY 321         // conv-out rows needed (full rows 32..352)
#define OX 161         // conv-out cols needed (full cols 32..192)
#define HC 320
#define WC 160
#define LCOLS 128      // staged cols per WG
#define PITCH 88       // rows staged per col: 64 + 24 (waves at y0+8w) ; 176B = 16B-mult
#define BLKS_PER_BATCH 7200

__device__ __forceinline__ u16 bf16rtn(float v) {
    union { float f; unsigned u; } U; U.f = v;
    unsigned r = U.u + 0x7fffu + ((U.u >> 16) & 1u);
    return (u16)(r >> 16);
}
__device__ __forceinline__ float bf16tof(u16 h) {
    union { float f; unsigned u; } U; U.u = ((unsigned)h) << 16; return U.f;
}

__device__ __forceinline__ float wave_max(float v) {
    #pragma unroll
    for (int off = 32; off > 0; off >>= 1) v = fmaxf(v, __shfl_down(v, off, 64));
    return v;
}
__device__ __forceinline__ float wave_sum(float v) {
    #pragma unroll
    for (int off = 32; off > 0; off >>= 1) v += __shfl_down(v, off, 64);
    return v;
}

// Split fp32 weights into bf16 hi/lo planes, transposed to [b][r48][c][kx][ky], r>=36 zeroed.
__global__ __launch_bounds__(256) void prep_weights(
    const float* __restrict__ wk, u16* __restrict__ wh, u16* __restrict__ wl)
{
    int d = blockIdx.x * 256 + threadIdx.x;           // [0, 4*48*3*64*64)
    int ky = d & 63;
    int kx = (d >> 6) & 63;
    int rc = d >> 12;                                  // (b*48+r)*3 + c
    int c  = rc % 3;
    int br = rc / 3;
    int r  = br % RP;
    int b  = br / RP;
    float v = 0.f;
    if (r < R_) v = wk[(((size_t)(b*R_ + r)*C_ + c)*KS + (size_t)ky)*KS + kx];
    u16 h = bf16rtn(v);
    float lo = v - bf16tof(h);
    wh[d] = h;
    wl[d] = bf16rtn(lo);
}

// Implicit-GEMM conv via MFMA 16x16x32 bf16, 3-product hi/lo split.
// Round-8 structure: 4 waves = 4 y-rows (y0 + 8*wave); each wave walks the
// FULL K (no k-split, no cross-wave reduction, acc = 48 regs -> 3 waves/SIMD).
// All waves issue identical A-load addresses -> L1 serves 3 of 4 waves.
// All acc indices are compile-time constants (r5 spill lesson).
template<int NT>
__device__ __forceinline__ void conv_body(
    const float* __restrict__ in, const u16* __restrict__ wth, const u16* __restrict__ wtl,
    float* __restrict__ out, u16* Lh, u16* Ll, int x0, int y0)
{
    const int b    = blockIdx.z;
    const int t    = threadIdx.x;
    const int w    = __builtin_amdgcn_readfirstlane(t >> 6);   // wave's y index
    const int lane = t & 63;
    const int nu   = lane & 15;
    const int q    = lane >> 4;

    f32x4 acc[3][NT];
    #pragma unroll
    for (int mi = 0; mi < 3; mi++)
        #pragma unroll
        for (int n = 0; n < NT; n++)
            acc[mi][n] = (f32x4){0.f, 0.f, 0.f, 0.f};

    for (int c = 0; c < C_; c++) {
        __syncthreads();   // protect previous channel's reads
        // ---- stage rows y0..y0+87, cols x0..x0+127, transposed + bf16-split ----
        // 44 row-pairs x 32 float4-cols = 1408 items over 256 threads (6 iters).
        const float* src = in + ((size_t)(b*C_ + c))*H_*W_;
        #pragma unroll
        for (int k = 0; k < 6; k++) {
            int idx = t + 256*k;
            if (idx < 1408) {
                int pair = idx >> 5;         // 0..43
                int r0   = pair * 2;
                int c4   = (idx & 31) * 4;
                int gx   = x0 + c4;
                int gy   = y0 + r0;
                float4 va = make_float4(0.f,0.f,0.f,0.f), vb = va;
                if (gx < W_) {               // float4 chunks entirely in or out
                    if (gy < H_)     va = *(const float4*)(src + (size_t)gy*W_ + gx);
                    if (gy + 1 < H_) vb = *(const float4*)(src + (size_t)(gy+1)*W_ + gx);
                }
                const float* pa = &va.x;
                const float* pb = &vb.x;
                #pragma unroll
                for (int j = 0; j < 4; j++) {
                    int col = c4 + j;
                    u16 ha = bf16rtn(pa[j]);
                    u16 hb = bf16rtn(pb[j]);
                    u16 la = bf16rtn(pa[j] - bf16tof(ha));
                    u16 lb = bf16rtn(pb[j] - bf16tof(hb));
                    *(unsigned*)&Lh[col*PITCH + r0] = (unsigned)ha | ((unsigned)hb << 16);
                    *(unsigned*)&Ll[col*PITCH + r0] = (unsigned)la | ((unsigned)lb << 16);
                }
            }
        }
        __syncthreads();

        // ---- MFMA; every wave walks ALL kx (same A addresses -> L1 reuse) ----
        #pragma unroll 1
        for (int kx = 0; kx < KS; kx++) {
            #pragma unroll
            for (int kycI = 0; kycI < 2; kycI++) {
                int kyc = kycI * 32;
                bf16x8 Ah[3], Al[3];
                #pragma unroll
                for (int mi = 0; mi < 3; mi++) {
                    size_t off = ((((size_t)(b*RP + mi*16 + nu)*C_ + c)*KS + kx)*KS) + kyc + 8*q;
                    Ah[mi] = *(const bf16x8*)(wth + off);
                    Al[mi] = *(const bf16x8*)(wtl + off);
                }
                // wave's y offset = +8*w rows
                const u16* colbase = Lh + (size_t)(nu + kx)*PITCH + kyc + 8*q + 8*w;
                #pragma unroll
                for (int n = 0; n < NT; n++) {
                    const u16* ph = colbase + n*16*PITCH;
                    bf16x8 Bh = *(const bf16x8*)ph;
                    bf16x8 Bl = *(const bf16x8*)(ph + (size_t)LCOLS*PITCH);
                    #pragma unroll
                    for (int mi = 0; mi < 3; mi++) {
                        acc[mi][n] = __builtin_amdgcn_mfma_f32_16x16x32_bf16(Ah[mi], Bh, acc[mi][n], 0, 0, 0);
                        acc[mi][n] = __builtin_amdgcn_mfma_f32_16x16x32_bf16(Ah[mi], Bl, acc[mi][n], 0, 0, 0);
                        acc[mi][n] = __builtin_amdgcn_mfma_f32_16x16x32_bf16(Al[mi], Bh, acc[mi][n], 0, 0, 0);
                    }
                }
            }
        }
    }

    // ---- direct epilogue: wave owns its y completely; coalesced stores ----
    const int y = y0 + 8*w;
    if (y <= 320) {
        #pragma unroll
        for (int mi = 0; mi < 3; mi++) {
            #pragma unroll
            for (int n = 0; n < NT; n++) {
                #pragma unroll
                for (int i = 0; i < 4; i++) {
                    int r = mi*16 + q*4 + i;     // C/D: row = (lane>>4)*4 + reg
                    int x = x0 + n*16 + nu;      //      col = lane&15
                    if (r < R_ && x < OX)
                        out[((size_t)(b*R_ + r)*OY + y)*OX + x] = acc[mi][n][i];
                }
            }
        }
    }
}

__global__ __launch_bounds__(256) void conv_mfma(
    const float* __restrict__ in, const u16* __restrict__ wth, const u16* __restrict__ wtl,
    float* __restrict__ out)
{
    __shared__ u16 smem[2 * LCOLS * PITCH];   // 45056 B
    u16* Lh = smem;
    u16* Ll = smem + LCOLS * PITCH;
    // y mapping: slot s<80 -> y0 = 32*(s>>3) + (s&7); waves cover y0+{0,8,16,24}.
    // s==80 -> y0 = 320 (waves 1..3 compute on zero-padded rows, skip write).
    const int s = blockIdx.y;
    const int y0 = (s < 80) ? (((s >> 3) << 5) + (s & 7)) : 320;

    if (blockIdx.x == 0)      conv_body<4>(in, wth, wtl, out, Lh, Ll, 0,   y0);
    else if (blockIdx.x == 1) conv_body<4>(in, wth, wtl, out, Lh, Ll, 64,  y0);
    else                      conv_body<3>(in, wth, wtl, out, Lh, Ll, 128, y0);
}

// Bilinear resize (iy==i, ix==j for the needed range) + per-block max partials.
__global__ __launch_bounds__(256) void resize_kernel(
    const float* __restrict__ cv, float* __restrict__ out, float* __restrict__ pmax)
{
    const int t = threadIdx.x;
    const int idx = blockIdx.x * 256 + t;
    const int j = idx % WC;
    const int rest = idx / WC;
    const int i = rest % HC;
    const int br = rest / HC;

    float fy = (i + 32.5f) * (1.0f/384.0f);
    float fx = (j + 32.5f) * (1.0f/224.0f);

    const float* p = cv + ((size_t)br*OY + i)*OX + j;
    float v00 = p[0], v01 = p[1], v10 = p[OX], v11 = p[OX+1];
    float v = (1.f-fy)*((1.f-fx)*v00 + fx*v01) + fy*((1.f-fx)*v10 + fx*v11);
    out[idx] = v;

    __shared__ float sm[4];
    float m = wave_max(v);
    if ((t & 63) == 0) sm[t >> 6] = m;
    __syncthreads();
    if (t == 0) pmax[blockIdx.x] = fmaxf(fmaxf(sm[0], sm[1]), fmaxf(sm[2], sm[3]));
}

__global__ __launch_bounds__(256) void reduce_kernel(
    const float* __restrict__ part, float* __restrict__ res, int n, int is_sum)
{
    const int b = blockIdx.x;
    const int t = threadIdx.x;
    const float* p = part + (size_t)b*n;
    float v = is_sum ? 0.f : -3.0e38f;
    for (int k = t; k < n; k += 256) v = is_sum ? (v + p[k]) : fmaxf(v, p[k]);
    __shared__ float sm[4];
    float w = is_sum ? wave_sum(v) : wave_max(v);
    if ((t & 63) == 0) sm[t >> 6] = w;
    __syncthreads();
    if (t == 0) {
        res[b] = is_sum ? (sm[0]+sm[1]+sm[2]+sm[3])
                        : fmaxf(fmaxf(sm[0], sm[1]), fmaxf(sm[2], sm[3]));
    }
}

__global__ __launch_bounds__(256) void exp_kernel(
    float* __restrict__ out, const float* __restrict__ bmax, float* __restrict__ psum)
{
    const int t = threadIdx.x;
    const int idx = blockIdx.x * 256 + t;
    const int b = blockIdx.x / BLKS_PER_BATCH;
    float e = expf(out[idx] - bmax[b]);
    out[idx] = e;
    __shared__ float sm[4];
    float s = wave_sum(e);
    if ((t & 63) == 0) sm[t >> 6] = s;
    __syncthreads();
    if (t == 0) psum[blockIdx.x] = sm[0]+sm[1]+sm[2]+sm[3];
}

__global__ __launch_bounds__(256) void scale_kernel(
    float* __restrict__ out, const float* __restrict__ bsum)
{
    const int idx = blockIdx.x * 256 + threadIdx.x;
    const int b = blockIdx.x / BLKS_PER_BATCH;
    out[idx] = out[idx] / bsum[b];
}

extern "C" void kernel_launch(void* const* d_in, const int* in_sizes, int n_in,
                              void* d_out, int out_size, void* d_ws, size_t ws_size,
                              hipStream_t stream)
{
    const float* logits = (const float*)d_in[0];   // (4,3,384,224) fp32
    const float* wk     = (const float*)d_in[1];   // (144,3,64,64) fp32
    float* out = (float*)d_out;                    // (4,36,320,160) fp32
    char*  wsB = (char*)d_ws;

    // workspace layout (bytes)
    float* convOut = (float*)wsB;                              // 7,442,064 f32 = 29,768,256 B
    u16*   wth     = (u16*)(wsB + 29768256);                   // 2,359,296 u16 = 4,718,592 B
    u16*   wtl     = (u16*)(wsB + 29768256 + 4718592);         // 4,718,592 B
    float* pmax    = (float*)(wsB + 29768256 + 2*4718592);     // 28800 f32
    float* psum    = pmax + 28800;
    float* bmax    = psum + 28800;
    float* bsum    = bmax + 8;

    hipLaunchKernelGGL(prep_weights, dim3(9216),  dim3(256), 0, stream, wk, wth, wtl);
    hipLaunchKernelGGL(conv_mfma,    dim3(3, 81, B_), dim3(256), 0, stream, logits, wth, wtl, convOut);
    hipLaunchKernelGGL(resize_kernel, dim3(28800), dim3(256), 0, stream, convOut, out, pmax);
    hipLaunchKernelGGL(reduce_kernel, dim3(4),     dim3(256), 0, stream, pmax, bmax, BLKS_PER_BATCH, 0);
    hipLaunchKernelGGL(exp_kernel,    dim3(28800), dim3(256), 0, stream, out, bmax, psum);
    hipLaunchKernelGGL(reduce_kernel, dim3(4),     dim3(256), 0, stream, psum, bsum, BLKS_PER_BATCH, 1);
    hipLaunchKernelGGL(scale_kernel,  dim3(28800), dim3(256), 0, stream, out, bsum);
}

// Round 9
// 794.971 us; speedup vs baseline: 1.4661x; 1.4661x over previous
//
#include <hip/hip_runtime.h>

typedef short bf16x8 __attribute__((ext_vector_type(8)));
typedef float f32x4  __attribute__((ext_vector_type(4)));
typedef unsigned short u16;

#define B_ 4
#define R_ 36
#define RP 48          // r padded to 3 m-tiles of 16
#define C_ 3
#define H_ 384
#define W_ 224
#define KS 64
#define OY 321         // conv-out rows needed (full rows 32..352)
#define OX 161         // conv-out cols needed (full cols 32..192)
#define HC 320
#define WC 160
#define LCOLS 128      // staged cols per WG
#define PITCH 72       // rows staged per col (64 + 8 halo for second y); u16 units
#define BLKS_PER_BATCH 7200

__device__ __forceinline__ u16 bf16rtn(float v) {
    union { float f; unsigned u; } U; U.f = v;
    unsigned r = U.u + 0x7fffu + ((U.u >> 16) & 1u);
    return (u16)(r >> 16);
}
__device__ __forceinline__ float bf16tof(u16 h) {
    union { float f; unsigned u; } U; U.u = ((unsigned)h) << 16; return U.f;
}

__device__ __forceinline__ float wave_max(float v) {
    #pragma unroll
    for (int off = 32; off > 0; off >>= 1) v = fmaxf(v, __shfl_down(v, off, 64));
    return v;
}
__device__ __forceinline__ float wave_sum(float v) {
    #pragma unroll
    for (int off = 32; off > 0; off >>= 1) v += __shfl_down(v, off, 64);
    return v;
}

// Split fp32 weights into bf16 hi/lo planes, transposed to [b][r48][c][kx][ky], r>=36 zeroed.
__global__ __launch_bounds__(256) void prep_weights(
    const float* __restrict__ wk, u16* __restrict__ wh, u16* __restrict__ wl)
{
    int d = blockIdx.x * 256 + threadIdx.x;           // [0, 4*48*3*64*64)
    int ky = d & 63;
    int kx = (d >> 6) & 63;
    int rc = d >> 12;                                  // (b*48+r)*3 + c
    int c  = rc % 3;
    int br = rc / 3;
    int r  = br % RP;
    int b  = br / RP;
    float v = 0.f;
    if (r < R_) v = wk[(((size_t)(b*R_ + r)*C_ + c)*KS + (size_t)ky)*KS + kx];
    u16 h = bf16rtn(v);
    float lo = v - bf16tof(h);
    wh[d] = h;
    wl[d] = bf16rtn(lo);
}

__device__ __forceinline__ void loadA(
    const u16* __restrict__ wth, const u16* __restrict__ wtl,
    int b, int c, int kx, int kyc, int nu, int q,
    bf16x8 (&Ah)[3], bf16x8 (&Al)[3])
{
    #pragma unroll
    for (int mi = 0; mi < 3; mi++) {
        size_t off = ((((size_t)(b*RP + mi*16 + nu)*C_ + c)*KS + kx)*KS) + kyc + 8*q;
        Ah[mi] = *(const bf16x8*)(wth + off);
        Al[mi] = *(const bf16x8*)(wtl + off);
    }
}

// Implicit-GEMM conv via MFMA 16x16x32 bf16, 3-product hi/lo split.
// r7 structure (2 y-rows per WG, 4 waves k-split, best MFMA:A-load ratio) +
// r9: X/Y double-buffered A-prefetch one chunk ahead (NO min-waves launch
// bound -- that's what spilled r3). All acc indices compile-time (r5 lesson).
template<int NT>
__device__ __forceinline__ void computeChunk(
    const u16* __restrict__ Lh, int kx, int kyc, int nu, int q,
    const bf16x8 (&Ah)[3], const bf16x8 (&Al)[3], f32x4 (&acc)[2][3][NT])
{
    const u16* colbase = Lh + (size_t)(nu + kx)*PITCH + kyc + 8*q;
    #pragma unroll
    for (int n = 0; n < NT; n++) {
        const u16* ph = colbase + n*16*PITCH;
        bf16x8 Bh0 = *(const bf16x8*)ph;
        bf16x8 Bl0 = *(const bf16x8*)(ph + (size_t)LCOLS*PITCH);
        #pragma unroll
        for (int mi = 0; mi < 3; mi++) {
            acc[0][mi][n] = __builtin_amdgcn_mfma_f32_16x16x32_bf16(Ah[mi], Bh0, acc[0][mi][n], 0, 0, 0);
            acc[0][mi][n] = __builtin_amdgcn_mfma_f32_16x16x32_bf16(Ah[mi], Bl0, acc[0][mi][n], 0, 0, 0);
            acc[0][mi][n] = __builtin_amdgcn_mfma_f32_16x16x32_bf16(Al[mi], Bh0, acc[0][mi][n], 0, 0, 0);
        }
        bf16x8 Bh1 = *(const bf16x8*)(ph + 8);                        // second y: +8 rows
        bf16x8 Bl1 = *(const bf16x8*)(ph + (size_t)LCOLS*PITCH + 8);
        #pragma unroll
        for (int mi = 0; mi < 3; mi++) {
            acc[1][mi][n] = __builtin_amdgcn_mfma_f32_16x16x32_bf16(Ah[mi], Bh1, acc[1][mi][n], 0, 0, 0);
            acc[1][mi][n] = __builtin_amdgcn_mfma_f32_16x16x32_bf16(Ah[mi], Bl1, acc[1][mi][n], 0, 0, 0);
            acc[1][mi][n] = __builtin_amdgcn_mfma_f32_16x16x32_bf16(Al[mi], Bh1, acc[1][mi][n], 0, 0, 0);
        }
    }
}

template<int NT>
__device__ __forceinline__ void conv_body(
    const float* __restrict__ in, const u16* __restrict__ wth, const u16* __restrict__ wtl,
    float* __restrict__ out, u16* Lh, u16* Ll, int x0, int y0, bool has2)
{
    const int b    = blockIdx.z;
    const int t    = threadIdx.x;
    const int w    = t >> 6;
    const int lane = t & 63;
    const int nu   = lane & 15;
    const int q    = lane >> 4;

    f32x4 acc[2][3][NT];
    #pragma unroll
    for (int yi = 0; yi < 2; yi++)
        #pragma unroll
        for (int mi = 0; mi < 3; mi++)
            #pragma unroll
            for (int n = 0; n < NT; n++)
                acc[yi][mi][n] = (f32x4){0.f, 0.f, 0.f, 0.f};

    bf16x8 AhX[3], AlX[3], AhY[3], AlY[3];
    loadA(wth, wtl, b, 0, w, 0, nu, q, AhX, AlX);   // first chunk, in flight over staging

    for (int c = 0; c < C_; c++) {
        __syncthreads();   // protect previous channel's reads
        // ---- stage rows y0..y0+71, cols x0..x0+127, transposed + bf16-split ----
        const float* src = in + ((size_t)(b*C_ + c))*H_*W_;
        #pragma unroll
        for (int k = 0; k < 5; k++) {
            int idx = t + 256*k;
            if (idx < 1152) {
                int pair = idx >> 5;         // 0..35
                int r0   = pair * 2;
                int c4   = (idx & 31) * 4;
                int gx   = x0 + c4;
                int gy   = y0 + r0;
                float4 va = make_float4(0.f,0.f,0.f,0.f), vb = va;
                if (gx < W_) {               // float4 chunks entirely in or out
                    if (gy < H_)     va = *(const float4*)(src + (size_t)gy*W_ + gx);
                    if (gy + 1 < H_) vb = *(const float4*)(src + (size_t)(gy+1)*W_ + gx);
                }
                const float* pa = &va.x;
                const float* pb = &vb.x;
                #pragma unroll
                for (int j = 0; j < 4; j++) {
                    int col = c4 + j;
                    u16 ha = bf16rtn(pa[j]);
                    u16 hb = bf16rtn(pb[j]);
                    u16 la = bf16rtn(pa[j] - bf16tof(ha));
                    u16 lb = bf16rtn(pb[j] - bf16tof(hb));
                    *(unsigned*)&Lh[col*PITCH + r0] = (unsigned)ha | ((unsigned)hb << 16);
                    *(unsigned*)&Ll[col*PITCH + r0] = (unsigned)la | ((unsigned)lb << 16);
                }
            }
        }
        __syncthreads();

        // ---- pipelined MFMA; wave w owns kx in {w, w+4, ..., w+60} ----
        #pragma unroll 1
        for (int kxi = 0; kxi < 16; kxi++) {
            int kx = kxi*4 + w;
            loadA(wth, wtl, b, c, kx, 32, nu, q, AhY, AlY);          // prefetch (kx,32)
            computeChunk<NT>(Lh, kx, 0, nu, q, AhX, AlX, acc);
            if (kxi < 15) {
                loadA(wth, wtl, b, c, kx + 4, 0, nu, q, AhX, AlX);   // prefetch (kx+4,0)
            } else if (c + 1 < C_) {
                loadA(wth, wtl, b, c + 1, w, 0, nu, q, AhX, AlX);    // next channel (crosses barrier)
            }
            computeChunk<NT>(Lh, kx, 32, nu, q, AhY, AlY, acc);
        }
    }

    // ---- k-split reduction across 4 waves: chunks of 6 frags, FULLY unrolled ----
    float* red = (float*)Lh;   // [4 waves][6 frags][64 lanes][4] f32 = 24576 B <= smem
    const int lsrc = t >> 2;
    const int isrc = t & 3;
    constexpr int F = 2 * 3 * NT;
    #pragma unroll
    for (int base = 0; base < F; base += 6) {
        __syncthreads();
        #pragma unroll
        for (int k = 0; k < 6; k++) {
            if (base + k < F) {
                constexpr int TN = 3 * NT;
                int f = base + k;          // folds to constant under full unroll
                *(f32x4*)&red[((w*6 + k)*64 + lane)*4] = acc[f/TN][(f%TN)/NT][(f%TN)%NT];
            }
        }
        __syncthreads();
        #pragma unroll
        for (int k = 0; k < 6; k++) {
            if (base + k < F) {
                float s = red[((0*6+k)*64 + lsrc)*4 + isrc]
                        + red[((1*6+k)*64 + lsrc)*4 + isrc]
                        + red[((2*6+k)*64 + lsrc)*4 + isrc]
                        + red[((3*6+k)*64 + lsrc)*4 + isrc];
                int f  = base + k;
                int yi = f / (3*NT);
                int mi = (f % (3*NT)) / NT;
                int n  = f % NT;
                int r  = mi*16 + (lsrc >> 4)*4 + isrc;
                int x  = x0 + n*16 + (lsrc & 15);
                int y  = y0 + yi*8;
                if (r < R_ && x < OX && (yi == 0 || has2))
                    out[((size_t)(b*R_ + r)*OY + y)*OX + x] = s;
            }
        }
    }
}

__global__ __launch_bounds__(256) void conv_mfma(
    const float* __restrict__ in, const u16* __restrict__ wth, const u16* __restrict__ wtl,
    float* __restrict__ out)
{
    __shared__ u16 smem[2 * LCOLS * PITCH];   // 36864 B; reused for reduction
    u16* Lh = smem;
    u16* Ll = smem + LCOLS * PITCH;
    // y mapping: by<160 -> y0 = 16*(by>>3) + (by&7), pair (y0, y0+8); by==160 -> y=320 alone
    const int by = blockIdx.y;
    int y0; bool has2;
    if (by < 160) { y0 = ((by >> 3) << 4) + (by & 7); has2 = true; }
    else          { y0 = 320; has2 = false; }

    if (blockIdx.x == 0)      conv_body<4>(in, wth, wtl, out, Lh, Ll, 0,   y0, has2);
    else if (blockIdx.x == 1) conv_body<4>(in, wth, wtl, out, Lh, Ll, 64,  y0, has2);
    else                      conv_body<3>(in, wth, wtl, out, Lh, Ll, 128, y0, has2);
}

// Bilinear resize (iy==i, ix==j for the needed range) + per-block max partials.
__global__ __launch_bounds__(256) void resize_kernel(
    const float* __restrict__ cv, float* __restrict__ out, float* __restrict__ pmax)
{
    const int t = threadIdx.x;
    const int idx = blockIdx.x * 256 + t;
    const int j = idx % WC;
    const int rest = idx / WC;
    const int i = rest % HC;
    const int br = rest / HC;

    float fy = (i + 32.5f) * (1.0f/384.0f);
    float fx = (j + 32.5f) * (1.0f/224.0f);

    const float* p = cv + ((size_t)br*OY + i)*OX + j;
    float v00 = p[0], v01 = p[1], v10 = p[OX], v11 = p[OX+1];
    float v = (1.f-fy)*((1.f-fx)*v00 + fx*v01) + fy*((1.f-fx)*v10 + fx*v11);
    out[idx] = v;

    __shared__ float sm[4];
    float m = wave_max(v);
    if ((t & 63) == 0) sm[t >> 6] = m;
    __syncthreads();
    if (t == 0) pmax[blockIdx.x] = fmaxf(fmaxf(sm[0], sm[1]), fmaxf(sm[2], sm[3]));
}

__global__ __launch_bounds__(256) void reduce_kernel(
    const float* __restrict__ part, float* __restrict__ res, int n, int is_sum)
{
    const int b = blockIdx.x;
    const int t = threadIdx.x;
    const float* p = part + (size_t)b*n;
    float v = is_sum ? 0.f : -3.0e38f;
    for (int k = t; k < n; k += 256) v = is_sum ? (v + p[k]) : fmaxf(v, p[k]);
    __shared__ float sm[4];
    float w = is_sum ? wave_sum(v) : wave_max(v);
    if ((t & 63) == 0) sm[t >> 6] = w;
    __syncthreads();
    if (t == 0) {
        res[b] = is_sum ? (sm[0]+sm[1]+sm[2]+sm[3])
                        : fmaxf(fmaxf(sm[0], sm[1]), fmaxf(sm[2], sm[3]));
    }
}

__global__ __launch_bounds__(256) void exp_kernel(
    float* __restrict__ out, const float* __restrict__ bmax, float* __restrict__ psum)
{
    const int t = threadIdx.x;
    const int idx = blockIdx.x * 256 + t;
    const int b = blockIdx.x / BLKS_PER_BATCH;
    float e = expf(out[idx] - bmax[b]);
    out[idx] = e;
    __shared__ float sm[4];
    float s = wave_sum(e);
    if ((t & 63) == 0) sm[t >> 6] = s;
    __syncthreads();
    if (t == 0) psum[blockIdx.x] = sm[0]+sm[1]+sm[2]+sm[3];
}

__global__ __launch_bounds__(256) void scale_kernel(
    float* __restrict__ out, const float* __restrict__ bsum)
{
    const int idx = blockIdx.x * 256 + threadIdx.x;
    const int b = blockIdx.x / BLKS_PER_BATCH;
    out[idx] = out[idx] / bsum[b];
}

extern "C" void kernel_launch(void* const* d_in, const int* in_sizes, int n_in,
                              void* d_out, int out_size, void* d_ws, size_t ws_size,
                              hipStream_t stream)
{
    const float* logits = (const float*)d_in[0];   // (4,3,384,224) fp32
    const float* wk     = (const float*)d_in[1];   // (144,3,64,64) fp32
    float* out = (float*)d_out;                    // (4,36,320,160) fp32
    char*  wsB = (char*)d_ws;

    // workspace layout (bytes)
    float* convOut = (float*)wsB;                              // 7,442,064 f32 = 29,768,256 B
    u16*   wth     = (u16*)(wsB + 29768256);                   // 2,359,296 u16 = 4,718,592 B
    u16*   wtl     = (u16*)(wsB + 29768256 + 4718592);         // 4,718,592 B
    float* pmax    = (float*)(wsB + 29768256 + 2*4718592);     // 28800 f32
    float* psum    = pmax + 28800;
    float* bmax    = psum + 28800;
    float* bsum    = bmax + 8;

    hipLaunchKernelGGL(prep_weights, dim3(9216),  dim3(256), 0, stream, wk, wth, wtl);
    hipLaunchKernelGGL(conv_mfma,    dim3(3, 161, B_), dim3(256), 0, stream, logits, wth, wtl, convOut);
    hipLaunchKernelGGL(resize_kernel, dim3(28800), dim3(256), 0, stream, convOut, out, pmax);
    hipLaunchKernelGGL(reduce_kernel, dim3(4),     dim3(256), 0, stream, pmax, bmax, BLKS_PER_BATCH, 0);
    hipLaunchKernelGGL(exp_kernel,    dim3(28800), dim3(256), 0, stream, out, bmax, psum);
    hipLaunchKernelGGL(reduce_kernel, dim3(4),     dim3(256), 0, stream, psum, bsum, BLKS_PER_BATCH, 1);
    hipLaunchKernelGGL(scale_kernel,  dim3(28800), dim3(256), 0, stream, out, bsum);
}

// Round 10
// 703.081 us; speedup vs baseline: 1.6577x; 1.1307x over previous
//
#include <hip/hip_runtime.h>

typedef short bf16x8 __attribute__((ext_vector_type(8)));
typedef float f32x4  __attribute__((ext_vector_type(4)));
typedef unsigned short u16;

#define B_ 4
#define R_ 36
#define RP 48          // r padded to 3 m-tiles of 16
#define C_ 3
#define H_ 384
#define W_ 224
#define KS 64
#define OY 321         // conv-out rows needed
#define OX 161         // conv-out cols needed
#define HC 320
#define WC 160
#define LCOLS 128      // staged cols per WG
#define PITCH 88       // B rows per col: 64 + 24 (waves at y0+8w); 176 B, 16B-mult
#define CHUNK 6144     // u16 per A-chunk: 2 planes x 48 r x 64 ky (12 KB)
#define BLKS_PER_BATCH 7200

__device__ __forceinline__ u16 bf16rtn(float v) {
    union { float f; unsigned u; } U; U.f = v;
    unsigned r = U.u + 0x7fffu + ((U.u >> 16) & 1u);
    return (u16)(r >> 16);
}
__device__ __forceinline__ float bf16tof(u16 h) {
    union { float f; unsigned u; } U; U.u = ((unsigned)h) << 16; return U.f;
}

__device__ __forceinline__ float wave_max(float v) {
    #pragma unroll
    for (int off = 32; off > 0; off >>= 1) v = fmaxf(v, __shfl_down(v, off, 64));
    return v;
}
__device__ __forceinline__ float wave_sum(float v) {
    #pragma unroll
    for (int off = 32; off > 0; off >>= 1) v += __shfl_down(v, off, 64);
    return v;
}

// Async 16B/lane global->LDS DMA (zero VGPR cost for the destination data).
__device__ __forceinline__ void dma16(const u16* g, u16* l) {
    __builtin_amdgcn_global_load_lds(
        (const __attribute__((address_space(1))) void*)g,
        (__attribute__((address_space(3))) void*)l, 16, 0, 0);
}

// Weights -> per-(b,c,kx) contiguous 12 KB chunks: [plane h/l][r48][ky64],
// with ky XOR-swizzle (ky ^ 8*(r&7)) so the A-frag ds_read_b128 pattern is
// bank-conflict-free while the chunk stays DMA-verbatim. r>=36 zeroed.
__global__ __launch_bounds__(256) void prep_weights(
    const float* __restrict__ wk, u16* __restrict__ wa)
{
    int d = blockIdx.x * 256 + threadIdx.x;   // [0, 768*6144 = 4,718,592)
    int ky    = d & 63;
    int t1    = d >> 6;
    int r     = t1 % 48;
    int t2    = t1 / 48;
    int plane = t2 & 1;
    int t3    = t2 >> 1;        // chunk index = (b*3+c)*64 + kx
    int kx    = t3 & 63;
    int bc    = t3 >> 6;
    int c     = bc % 3;
    int b     = bc / 3;
    float v = 0.f;
    if (r < R_) v = wk[(((size_t)(b*R_ + r)*C_ + c)*KS + ky)*KS + kx];
    u16 h = bf16rtn(v);
    u16 o = plane ? bf16rtn(v - bf16tof(h)) : h;
    int kySw = ky ^ ((r & 7) << 3);
    wa[(size_t)t3*CHUNK + plane*3072 + r*64 + kySw] = o;
}

// Implicit-GEMM conv, MFMA 16x16x32 bf16, 3-product hi/lo split.
// 4 waves = 4 y-rows (y0+8w); ALL waves share each kx chunk. A-operand is
// double-buffered in LDS, filled by async global_load_lds issued one chunk
// ahead (zero VGPRs -> no r9 occupancy cliff). Per-kx: waitcnt(0) on own DMA,
// raw s_barrier, issue next DMA, compute. acc = 48 regs, compile-time indexed.
template<int NT>
__device__ __forceinline__ void conv_body(
    const float* __restrict__ in, const u16* __restrict__ wa,
    float* __restrict__ out, u16* Lh, u16* Ll, u16* Ab, int x0, int y0)
{
    const int b    = blockIdx.z;
    const int t    = threadIdx.x;
    const int w    = __builtin_amdgcn_readfirstlane(t >> 6);
    const int lane = t & 63;
    const int nu   = lane & 15;
    const int q    = lane >> 4;

    f32x4 acc[3][NT];
    #pragma unroll
    for (int mi = 0; mi < 3; mi++)
        #pragma unroll
        for (int n = 0; n < NT; n++)
            acc[mi][n] = (f32x4){0.f, 0.f, 0.f, 0.f};

    const u16* wbase = wa + (size_t)(b*192)*CHUNK;   // this batch's 192 chunks

    // prologue: prefetch chunk g=0 into A-buf 0 (3 slices of 1 KB per wave)
    {
        const u16* src = wbase + (3*w)*512 + lane*8;
        u16* dst = Ab + (3*w)*512;
        dma16(src,        dst);
        dma16(src + 512,  dst + 512);
        dma16(src + 1024, dst + 1024);
    }

    for (int c = 0; c < C_; c++) {
        __syncthreads();
        // ---- stage B rows y0..y0+87, cols x0..x0+127, transposed + bf16-split ----
        const float* src = in + ((size_t)(b*C_ + c))*H_*W_;
        #pragma unroll
        for (int k = 0; k < 6; k++) {
            int idx = t + 256*k;
            if (idx < 1408) {
                int pair = idx >> 5;         // 0..43
                int r0   = pair * 2;
                int c4   = (idx & 31) * 4;
                int gx   = x0 + c4;
                int gy   = y0 + r0;
                float4 va = make_float4(0.f,0.f,0.f,0.f), vb = va;
                if (gx < W_) {               // float4 chunks entirely in or out
                    if (gy < H_)     va = *(const float4*)(src + (size_t)gy*W_ + gx);
                    if (gy + 1 < H_) vb = *(const float4*)(src + (size_t)(gy+1)*W_ + gx);
                }
                const float* pa = &va.x;
                const float* pb = &vb.x;
                #pragma unroll
                for (int j = 0; j < 4; j++) {
                    int col = c4 + j;
                    u16 ha = bf16rtn(pa[j]);
                    u16 hb = bf16rtn(pb[j]);
                    u16 la = bf16rtn(pa[j] - bf16tof(ha));
                    u16 lb = bf16rtn(pb[j] - bf16tof(hb));
                    *(unsigned*)&Lh[col*PITCH + r0] = (unsigned)ha | ((unsigned)hb << 16);
                    *(unsigned*)&Ll[col*PITCH + r0] = (unsigned)la | ((unsigned)lb << 16);
                }
            }
        }
        __syncthreads();

        // ---- pipelined kx loop: all waves, all kx ----
        #pragma unroll 1
        for (int kx = 0; kx < KS; kx++) {
            const int g = c*64 + kx;
            const int p = g & 1;
            __builtin_amdgcn_s_waitcnt(0x3F70);   // vmcnt(0): own prev-chunk DMA done
            __builtin_amdgcn_s_barrier();         // all waves' DMA done; buf p^1 free
            if (g + 1 < 192) {
                const u16* s2 = wbase + (size_t)(g+1)*CHUNK + (3*w)*512 + lane*8;
                u16* d2 = Ab + (p^1)*CHUNK + (3*w)*512;
                dma16(s2,        d2);
                dma16(s2 + 512,  d2 + 512);
                dma16(s2 + 1024, d2 + 1024);
            }
            const u16* Abp = Ab + p*CHUNK;
            #pragma unroll
            for (int kycI = 0; kycI < 2; kycI++) {
                const int kyc = kycI * 32;
                bf16x8 Ah[3], Al[3];
                #pragma unroll
                for (int mi = 0; mi < 3; mi++) {
                    int off = (mi*16 + nu)*64 + ((kyc + 8*q) ^ ((nu & 7) << 3));
                    Ah[mi] = *(const bf16x8*)(Abp + off);
                    Al[mi] = *(const bf16x8*)(Abp + 3072 + off);
                }
                const u16* colbase = Lh + (size_t)(nu + kx)*PITCH + kyc + 8*q + 8*w;
                #pragma unroll
                for (int n = 0; n < NT; n++) {
                    const u16* ph = colbase + n*16*PITCH;
                    bf16x8 Bh = *(const bf16x8*)ph;
                    bf16x8 Bl = *(const bf16x8*)(ph + (size_t)LCOLS*PITCH);
                    #pragma unroll
                    for (int mi = 0; mi < 3; mi++) {
                        acc[mi][n] = __builtin_amdgcn_mfma_f32_16x16x32_bf16(Ah[mi], Bh, acc[mi][n], 0, 0, 0);
                        acc[mi][n] = __builtin_amdgcn_mfma_f32_16x16x32_bf16(Ah[mi], Bl, acc[mi][n], 0, 0, 0);
                        acc[mi][n] = __builtin_amdgcn_mfma_f32_16x16x32_bf16(Al[mi], Bh, acc[mi][n], 0, 0, 0);
                    }
                }
            }
        }
    }

    // ---- direct epilogue: wave owns its y; coalesced stores, no reduction ----
    const int y = y0 + 8*w;
    if (y <= 320) {
        #pragma unroll
        for (int mi = 0; mi < 3; mi++) {
            #pragma unroll
            for (int n = 0; n < NT; n++) {
                #pragma unroll
                for (int i = 0; i < 4; i++) {
                    int r = mi*16 + q*4 + i;     // C/D: row = (lane>>4)*4 + reg
                    int x = x0 + n*16 + nu;      //      col = lane&15
                    if (r < R_ && x < OX)
                        out[((size_t)(b*R_ + r)*OY + y)*OX + x] = acc[mi][n][i];
                }
            }
        }
    }
}

__global__ __launch_bounds__(256) void conv_mfma(
    const float* __restrict__ in, const u16* __restrict__ wa, float* __restrict__ out)
{
    // B: 2 x 128*88 u16 = 45056 B; A: 2 bufs x 12288 B = 24576 B; total 69632 B
    __shared__ __align__(16) u16 smem[2*LCOLS*PITCH + 2*CHUNK];
    u16* Lh = smem;
    u16* Ll = smem + LCOLS*PITCH;
    u16* Ab = smem + 2*LCOLS*PITCH;
    // y mapping: s<80 -> y0 = 32*(s>>3) + (s&7); waves cover y0+{0,8,16,24}.
    // s==80 -> y0=320 (waves 1..3 compute on zero-fill, skip stores).
    const int s  = blockIdx.y;
    const int y0 = (s < 80) ? (((s >> 3) << 5) + (s & 7)) : 320;

    if (blockIdx.x == 0)      conv_body<4>(in, wa, out, Lh, Ll, Ab, 0,   y0);
    else if (blockIdx.x == 1) conv_body<4>(in, wa, out, Lh, Ll, Ab, 64,  y0);
    else                      conv_body<3>(in, wa, out, Lh, Ll, Ab, 128, y0);
}

// Bilinear resize (iy==i, ix==j for the needed range) + per-block max partials.
__global__ __launch_bounds__(256) void resize_kernel(
    const float* __restrict__ cv, float* __restrict__ out, float* __restrict__ pmax)
{
    const int t = threadIdx.x;
    const int idx = blockIdx.x * 256 + t;
    const int j = idx % WC;
    const int rest = idx / WC;
    const int i = rest % HC;
    const int br = rest / HC;

    float fy = (i + 32.5f) * (1.0f/384.0f);
    float fx = (j + 32.5f) * (1.0f/224.0f);

    const float* p = cv + ((size_t)br*OY + i)*OX + j;
    float v00 = p[0], v01 = p[1], v10 = p[OX], v11 = p[OX+1];
    float v = (1.f-fy)*((1.f-fx)*v00 + fx*v01) + fy*((1.f-fx)*v10 + fx*v11);
    out[idx] = v;

    __shared__ float sm[4];
    float m = wave_max(v);
    if ((t & 63) == 0) sm[t >> 6] = m;
    __syncthreads();
    if (t == 0) pmax[blockIdx.x] = fmaxf(fmaxf(sm[0], sm[1]), fmaxf(sm[2], sm[3]));
}

__global__ __launch_bounds__(256) void reduce_kernel(
    const float* __restrict__ part, float* __restrict__ res, int n, int is_sum)
{
    const int b = blockIdx.x;
    const int t = threadIdx.x;
    const float* p = part + (size_t)b*n;
    float v = is_sum ? 0.f : -3.0e38f;
    for (int k = t; k < n; k += 256) v = is_sum ? (v + p[k]) : fmaxf(v, p[k]);
    __shared__ float sm[4];
    float w = is_sum ? wave_sum(v) : wave_max(v);
    if ((t & 63) == 0) sm[t >> 6] = w;
    __syncthreads();
    if (t == 0) {
        res[b] = is_sum ? (sm[0]+sm[1]+sm[2]+sm[3])
                        : fmaxf(fmaxf(sm[0], sm[1]), fmaxf(sm[2], sm[3]));
    }
}

__global__ __launch_bounds__(256) void exp_kernel(
    float* __restrict__ out, const float* __restrict__ bmax, float* __restrict__ psum)
{
    const int t = threadIdx.x;
    const int idx = blockIdx.x * 256 + t;
    const int b = blockIdx.x / BLKS_PER_BATCH;
    float e = expf(out[idx] - bmax[b]);
    out[idx] = e;
    __shared__ float sm[4];
    float s = wave_sum(e);
    if ((t & 63) == 0) sm[t >> 6] = s;
    __syncthreads();
    if (t == 0) psum[blockIdx.x] = sm[0]+sm[1]+sm[2]+sm[3];
}

__global__ __launch_bounds__(256) void scale_kernel(
    float* __restrict__ out, const float* __restrict__ bsum)
{
    const int idx = blockIdx.x * 256 + threadIdx.x;
    const int b = blockIdx.x / BLKS_PER_BATCH;
    out[idx] = out[idx] / bsum[b];
}

extern "C" void kernel_launch(void* const* d_in, const int* in_sizes, int n_in,
                              void* d_out, int out_size, void* d_ws, size_t ws_size,
                              hipStream_t stream)
{
    const float* logits = (const float*)d_in[0];   // (4,3,384,224) fp32
    const float* wk     = (const float*)d_in[1];   // (144,3,64,64) fp32
    float* out = (float*)d_out;                    // (4,36,320,160) fp32
    char*  wsB = (char*)d_ws;

    // workspace layout (bytes) — same 39.4 MB footprint as previous rounds
    float* convOut = (float*)wsB;                              // 29,768,256 B
    u16*   wa      = (u16*)(wsB + 29768256);                   // 4,718,592 u16 = 9,437,184 B
    float* pmax    = (float*)(wsB + 29768256 + 9437184);       // 28800 f32
    float* psum    = pmax + 28800;
    float* bmax    = psum + 28800;
    float* bsum    = bmax + 8;

    hipLaunchKernelGGL(prep_weights, dim3(18432), dim3(256), 0, stream, wk, wa);
    hipLaunchKernelGGL(conv_mfma,    dim3(3, 81, B_), dim3(256), 0, stream, logits, wa, convOut);
    hipLaunchKernelGGL(resize_kernel, dim3(28800), dim3(256), 0, stream, convOut, out, pmax);
    hipLaunchKernelGGL(reduce_kernel, dim3(4),     dim3(256), 0, stream, pmax, bmax, BLKS_PER_BATCH, 0);
    hipLaunchKernelGGL(exp_kernel,    dim3(28800), dim3(256), 0, stream, out, bmax, psum);
    hipLaunchKernelGGL(reduce_kernel, dim3(4),     dim3(256), 0, stream, psum, bsum, BLKS_PER_BATCH, 1);
    hipLaunchKernelGGL(scale_kernel,  dim3(28800), dim3(256), 0, stream, out, bsum);
}